// Round 5
// baseline (1173.298 us; speedup 1.0000x reference)
//
#include <hip/hip_runtime.h>
#include <cstdint>
#include <cstddef>

#define D_DIM 256
#define T_DIM 512
#define B_DIM 128
#define S_DIM 512

typedef __attribute__((ext_vector_type(8))) short short8;
typedef __attribute__((ext_vector_type(4))) float f32x4;

// ---------- helpers ----------
__device__ inline unsigned short f2bf(float x) {
    unsigned u = __builtin_bit_cast(unsigned, x);
    unsigned r = (u + 0x7fffu + ((u >> 16) & 1u)) >> 16;
    return (unsigned short)r;
}
__device__ inline float bf2f(unsigned short b) {
    unsigned u = ((unsigned)b) << 16;
    return __builtin_bit_cast(float, u);
}
__device__ inline float fast_tanh(float x) {
    float ax = __builtin_fabsf(x);
    float e  = __expf(-2.0f * ax);
    float r  = (1.0f - e) * __builtin_amdgcn_rcpf(1.0f + e);
    return __builtin_copysignf(r, x);
}

// Truncation split: x = bf2f(hi) + lo-term; residual exact, lo truncated ->
// total err <= 2^-16 |x|.  Pair-packed: low 16 bits of .x = element 0.
__device__ inline void split4(float4 v, uint2& hi, uint2& lo) {
    unsigned u0 = __builtin_bit_cast(unsigned, v.x);
    unsigned u1 = __builtin_bit_cast(unsigned, v.y);
    unsigned u2 = __builtin_bit_cast(unsigned, v.z);
    unsigned u3 = __builtin_bit_cast(unsigned, v.w);
    hi.x = (u0 >> 16) | (u1 & 0xFFFF0000u);
    hi.y = (u2 >> 16) | (u3 & 0xFFFF0000u);
    float r0 = v.x - __builtin_bit_cast(float, u0 & 0xFFFF0000u);
    float r1 = v.y - __builtin_bit_cast(float, u1 & 0xFFFF0000u);
    float r2 = v.z - __builtin_bit_cast(float, u2 & 0xFFFF0000u);
    float r3 = v.w - __builtin_bit_cast(float, u3 & 0xFFFF0000u);
    lo.x = (__builtin_bit_cast(unsigned, r0) >> 16)
         | (__builtin_bit_cast(unsigned, r1) & 0xFFFF0000u);
    lo.y = (__builtin_bit_cast(unsigned, r2) >> 16)
         | (__builtin_bit_cast(unsigned, r3) & 0xFFFF0000u);
}

struct uint4s { unsigned x, y, z, w; };
__device__ inline short8 pack8(uint2 a, uint2 b) {
    uint4s u{a.x, a.y, b.x, b.y};
    return __builtin_bit_cast(short8, u);
}

// ---------- split-bf16 MFMA GEMM v2: C[M,N] = A @ B^T (+biases) ----------
// R4 analysis: GEMMs ~1.8x above HBM floor; half the staging (B planes) was
// pointless -- W is 256 KB, L2-resident, shared by every block.  v2: B
// fragments are converted fp32->bf16 hi/lo IN REGISTERS from global (L2-hot);
// LDS holds only the A hi/lo planes (32 KB, BK=64, XOR-swizzled as in R4).
// ll product dropped (err ~2^-22).  Grid: x = N-blocks (fastest) so adjacent
// dispatches share A rows.  128x128 tile, 4 waves of 64x64.
__global__ __launch_bounds__(256, 2)
void gemm_bt_mfma(const float* __restrict__ A, const float* __restrict__ Bm,
                  float* __restrict__ C,
                  const float* __restrict__ bias1, const float* __restrict__ bias2,
                  const int* __restrict__ ids, const float* __restrict__ emb,
                  int M, int N, int K)
{
    // LDS planes (bf16, [128 rows][64 k], row stride 128 B, swizzled):
    // Ahi @0, Alo @16K  -> 32 KB total.
    __shared__ char smem[32768];

    const int tid  = threadIdx.x;
    const int lane = tid & 63;
    const int quad = lane >> 4;
    const int lcol = lane & 15;
    const int wv   = tid >> 6;         // 4 waves: 2(M) x 2(N) of 64x64
    const int wm   = (wv & 1) * 64;
    const int wn   = (wv >> 1) * 64;
    const int m0   = blockIdx.y * 128;
    const int n0   = blockIdx.x * 128;

    // A staging map: thread covers rows rm+16i (i=0..7), float4-col kq.
    const int rm = tid >> 4;           // 0..15
    const int kq = tid & 15;           // 0..15  (float4 within BK=64)

    const float* arowp[8];
#pragma unroll
    for (int i = 0; i < 8; ++i) {
        int gm = m0 + rm + i * 16;
        arowp[i] = ids ? (emb + (size_t)ids[gm] * K) : (A + (size_t)gm * K);
    }
    int woff[8];
#pragma unroll
    for (int i = 0; i < 8; ++i) {
        int m = rm + i * 16;
        woff[i] = (m * 128 + kq * 8) ^ ((m & 7) << 4);
    }

    // B row pointers for this wave's 4 col-tiles (L2-resident W)
    const float* bptr[4];
#pragma unroll
    for (int nt = 0; nt < 4; ++nt) {
        int gn = n0 + wn + nt * 16 + lcol;
        bptr[nt] = Bm + (size_t)gn * K + quad * 8;
    }

    f32x4 acc[4][4];
#pragma unroll
    for (int mt = 0; mt < 4; ++mt)
#pragma unroll
        for (int nt = 0; nt < 4; ++nt) acc[mt][nt] = (f32x4){0.f, 0.f, 0.f, 0.f};

    // prologue: prefetch A for iter 0
    float4 pa[8];
#pragma unroll
    for (int i = 0; i < 8; ++i)
        pa[i] = *(const float4*)(arowp[i] + kq * 4);

    for (int it = 0; it < 4; ++it) {
        const int kc = it * 64;
        if (it) __syncthreads();       // prior tile's reads complete
#pragma unroll
        for (int i = 0; i < 8; ++i) {
            uint2 hi, lo;
            split4(pa[i], hi, lo);
            *(uint2*)(smem + 0     + woff[i]) = hi;
            *(uint2*)(smem + 16384 + woff[i]) = lo;
        }
        __syncthreads();

        if (it < 3) {                  // prefetch next A tile under compute
#pragma unroll
            for (int i = 0; i < 8; ++i)
                pa[i] = *(const float4*)(arowp[i] + kc + 64 + kq * 4);
        }

#pragma unroll
        for (int ks = 0; ks < 2; ++ks) {
            // B fragments: fp32 from global (L2-hot), convert in-register
            short8 bHi[4], bLo[4];
#pragma unroll
            for (int nt = 0; nt < 4; ++nt) {
                const float* bp = bptr[nt] + kc + ks * 32;
                float4 w0 = *(const float4*)(bp);
                float4 w1 = *(const float4*)(bp + 4);
                uint2 h0, l0, h1, l1;
                split4(w0, h0, l0);
                split4(w1, h1, l1);
                bHi[nt] = pack8(h0, h1);
                bLo[nt] = pack8(l0, l1);
            }
            short8 aHi[4], aLo[4];
#pragma unroll
            for (int mt = 0; mt < 4; ++mt) {
                int m = wm + mt * 16 + lcol;
                int off = (m * 128 + ks * 64 + quad * 16) ^ ((m & 7) << 4);
                aHi[mt] = *(const short8*)(smem + off);
                aLo[mt] = *(const short8*)(smem + 16384 + off);
            }
#pragma unroll
            for (int mt = 0; mt < 4; ++mt)
#pragma unroll
                for (int nt = 0; nt < 4; ++nt) {
                    acc[mt][nt] = __builtin_amdgcn_mfma_f32_16x16x32_bf16(aHi[mt], bHi[nt], acc[mt][nt], 0, 0, 0);
                    acc[mt][nt] = __builtin_amdgcn_mfma_f32_16x16x32_bf16(aLo[mt], bHi[nt], acc[mt][nt], 0, 0, 0);
                    acc[mt][nt] = __builtin_amdgcn_mfma_f32_16x16x32_bf16(aHi[mt], bLo[nt], acc[mt][nt], 0, 0, 0);
                }
        }
    }

    // epilogue: D row = quad*4 + reg, col = lcol (per 16x16 fragment)
    float bv[4];
#pragma unroll
    for (int nt = 0; nt < 4; ++nt) {
        int gn = n0 + wn + nt * 16 + lcol;
        float v = 0.f;
        if (bias1) v += bias1[gn];
        if (bias2) v += bias2[gn];
        bv[nt] = v;
    }
#pragma unroll
    for (int mt = 0; mt < 4; ++mt) {
        int gmb = m0 + wm + mt * 16 + quad * 4;
#pragma unroll
        for (int r = 0; r < 4; ++r) {
            float* crow = C + (size_t)(gmb + r) * N + n0 + wn;
#pragma unroll
            for (int nt = 0; nt < 4; ++nt)
                crow[nt * 16 + lcol] = acc[mt][nt][r] + bv[nt];
        }
    }
}

// LDS-only barrier (R1: neutral vs __syncthreads; kept, documents intent).
__device__ inline void lds_barrier() {
    asm volatile("s_waitcnt lgkmcnt(0)" ::: "memory");
    __builtin_amdgcn_s_barrier();
    __builtin_amdgcn_sched_barrier(0);
}

// ---------- MFMA Elman scan (R3 version, unchanged): A-row-packed ----------
// hh and lh share B=wh: h_hi in A-row 0, h_lo in A-row 1 -> one MFMA gives
// hh (C reg[0]) and lh (C reg[1]).  hl via B=wl on same packed A.  32
// MFMA/wave/step; measured 437 us (step 2049 cyc vs 1242-cyc MFMA floor).
__global__ __launch_bounds__(512) __attribute__((amdgpu_waves_per_eu(2, 2)))
void rnn_scan_mfma(const float* __restrict__ pre, const float* __restrict__ Whh,
                   float* __restrict__ hout)
{
    const int tid  = threadIdx.x;
    const int wave = tid >> 6;
    const int lane = tid & 63;
    const int quad = lane >> 4;
    const int lcol = lane & 15;
    const int b    = blockIdx.x;

    // LDS layout (shorts): Hh[0]@0, Hl[0]@256, Hh[1]@512, Hl[1]@768.
    __shared__ short lds[1024];
    for (int i = tid; i < 1024; i += 512) lds[i] = 0;

    // --- W fragments: B-operand layout, lane holds W[n=.., k=quad*8+j] ---
    short8 wh[2][8], wl[2][8];
#pragma unroll
    for (int tile = 0; tile < 2; ++tile) {
        const int n = wave * 32 + tile * 16 + lcol;
        const float* wr = Whh + (size_t)n * D_DIM + quad * 8;
#pragma unroll
        for (int kt = 0; kt < 8; ++kt) {
            float4 x0 = *(const float4*)(wr + kt * 32);
            float4 x1 = *(const float4*)(wr + kt * 32 + 4);
            float xs[8] = {x0.x, x0.y, x0.z, x0.w, x1.x, x1.y, x1.z, x1.w};
            short8 hi8, lo8;
#pragma unroll
            for (int j = 0; j < 8; ++j) {
                unsigned short h = f2bf(xs[j]);
                unsigned short l = f2bf(xs[j] - bf2f(h));
                hi8[j] = (short)h;
                lo8[j] = (short)l;
            }
            wh[tile][kt] = hi8;
            wl[tile][kt] = lo8;
        }
    }

    const bool active = (lane < 16);           // quad==0 holds C rows 0..3
    const int n0 = wave * 32 + lcol;           // tile 0 unit
    const int n1 = n0 + 16;                    // tile 1 unit
    const size_t rowbase = (size_t)b * T_DIM * D_DIM;

    // Persistent packed A fragment: row 0 (lanes lcol==0) = h_hi chunk,
    // row 1 (lanes lcol==1) = h_lo chunk, rows 2..15 permanently zero.
    const short8 ZS = {0, 0, 0, 0, 0, 0, 0, 0};
    short8 aP[8];
#pragma unroll
    for (int kt = 0; kt < 8; ++kt) aP[kt] = ZS;

    const int aq = quad * 8;                   // k-chunk within buffer

    // 2-step-deep pre pipeline: pv = step t, nv = step t+1
    float pv0 = 0.f, pv1 = 0.f, nv0 = 0.f, nv1 = 0.f;
    if (active) {
        pv0 = pre[rowbase + n0];
        pv1 = pre[rowbase + n1];
        nv0 = pre[rowbase + D_DIM + n0];
        nv1 = pre[rowbase + D_DIM + n1];
    }
    lds_barrier();

    const f32x4 Z = {0.f, 0.f, 0.f, 0.f};

    for (int t = 0; t < T_DIM; ++t) {
        // prefetch step t+2's pre
        float qv0 = 0.f, qv1 = 0.f;
        if (active && t + 2 < T_DIM) {
            const float* p2 = pre + rowbase + (size_t)(t + 2) * D_DIM;
            qv0 = p2[n0];
            qv1 = p2[n1];
        }

        // exec-masked A loads: lanes lcol==0 read h_hi, lcol==1 read h_lo
        const int bh = (t & 1) ? 512 : 0;
        if (lcol < 2) {
            const short* pa = lds + bh + lcol * 256 + aq;
#pragma unroll
            for (int kt = 0; kt < 8; ++kt)
                aP[kt] = *(const short8*)(pa + kt * 32);
        }

        // 4 chains: a1* (B=wh: row0=hh, row1=lh), a2* (B=wl: row0=hl)
        f32x4 a1t0, a1t1, a2t0, a2t1;
        a1t0 = __builtin_amdgcn_mfma_f32_16x16x32_bf16(aP[0], wh[0][0], Z, 0, 0, 0);
        a1t1 = __builtin_amdgcn_mfma_f32_16x16x32_bf16(aP[0], wh[1][0], Z, 0, 0, 0);
        a2t0 = __builtin_amdgcn_mfma_f32_16x16x32_bf16(aP[0], wl[0][0], Z, 0, 0, 0);
        a2t1 = __builtin_amdgcn_mfma_f32_16x16x32_bf16(aP[0], wl[1][0], Z, 0, 0, 0);
#pragma unroll
        for (int kt = 1; kt < 8; ++kt) {
            a1t0 = __builtin_amdgcn_mfma_f32_16x16x32_bf16(aP[kt], wh[0][kt], a1t0, 0, 0, 0);
            a1t1 = __builtin_amdgcn_mfma_f32_16x16x32_bf16(aP[kt], wh[1][kt], a1t1, 0, 0, 0);
            a2t0 = __builtin_amdgcn_mfma_f32_16x16x32_bf16(aP[kt], wl[0][kt], a2t0, 0, 0, 0);
            a2t1 = __builtin_amdgcn_mfma_f32_16x16x32_bf16(aP[kt], wl[1][kt], a2t1, 0, 0, 0);
        }

        // epilogue: lanes 0..15 hold C rows 0 (reg 0: hh/hl) and 1 (reg 1: lh)
        if (active) {
            const int wH = (t & 1) ? 0 : 512;   // write the other buffer
            float x0 = a1t0[0] + a1t0[1] + a2t0[0] + pv0;
            float x1 = a1t1[0] + a1t1[1] + a2t1[0] + pv1;
            float h0 = fast_tanh(x0);
            float h1 = fast_tanh(x1);
            hout[rowbase + (size_t)t * D_DIM + n0] = h0;   // stays in flight
            hout[rowbase + (size_t)t * D_DIM + n1] = h1;
            unsigned short h0h = f2bf(h0);
            unsigned short h0l = f2bf(h0 - bf2f(h0h));
            unsigned short h1h = f2bf(h1);
            unsigned short h1l = f2bf(h1 - bf2f(h1h));
            lds[wH + n0]       = (short)h0h;
            lds[wH + n1]       = (short)h1h;
            lds[wH + 256 + n0] = (short)h0l;
            lds[wH + 256 + n1] = (short)h1l;
        }
        pv0 = nv0; pv1 = nv1;
        nv0 = qv0; nv1 = qv1;
        lds_barrier();
    }
}

extern "C" void kernel_launch(void* const* d_in, const int* in_sizes, int n_in,
                              void* d_out, int out_size, void* d_ws, size_t ws_size,
                              hipStream_t stream)
{
    const int*   ids    = (const int*)  d_in[0];
    const float* emb    = (const float*)d_in[1];
    const float* W_ih0  = (const float*)d_in[2];
    const float* W_hh0  = (const float*)d_in[3];
    const float* b_ih0  = (const float*)d_in[4];
    const float* b_hh0  = (const float*)d_in[5];
    const float* W_ih1  = (const float*)d_in[6];
    const float* W_hh1  = (const float*)d_in[7];
    const float* b_ih1  = (const float*)d_in[8];
    const float* b_hh1  = (const float*)d_in[9];
    const float* W_head = (const float*)d_in[10];

    float* out = (float*)d_out;
    const int M = B_DIM * T_DIM;              // 65536
    float* pre0 = out;                        // d_out doubles as scratch
    float* pre1 = out + (size_t)M * D_DIM;
    float* h1   = (float*)d_ws;               // 64 MB of ws
    float* h2   = h1;

    // pre0 = emb[ids] @ W_ih0^T + (b_ih0 + b_hh0)   [grid: N-blocks fastest]
    gemm_bt_mfma<<<dim3(D_DIM / 128, M / 128), dim3(256), 0, stream>>>(
        nullptr, W_ih0, pre0, b_ih0, b_hh0, ids, emb, M, D_DIM, D_DIM);
    // layer-0 recurrence (MFMA, A-row-packed split-bf16, 1 batch row/block)
    rnn_scan_mfma<<<dim3(B_DIM), dim3(512), 0, stream>>>(pre0, W_hh0, h1);
    // pre1 = h1 @ W_ih1^T + (b_ih1 + b_hh1)
    gemm_bt_mfma<<<dim3(D_DIM / 128, M / 128), dim3(256), 0, stream>>>(
        h1, W_ih1, pre1, b_ih1, b_hh1, nullptr, nullptr, M, D_DIM, D_DIM);
    // layer-1 recurrence
    rnn_scan_mfma<<<dim3(B_DIM), dim3(512), 0, stream>>>(pre1, W_hh1, h2);
    // logits = h2 @ W_head^T
    gemm_bt_mfma<<<dim3(S_DIM / 128, M / 128), dim3(256), 0, stream>>>(
        h2, W_head, out, nullptr, nullptr, nullptr, nullptr, M, S_DIM, D_DIM);
}

// Round 7
// 1105.053 us; speedup vs baseline: 1.0618x; 1.0618x over previous
//
#include <hip/hip_runtime.h>
#include <cstdint>
#include <cstddef>

#define D_DIM 256
#define T_DIM 512
#define B_DIM 128
#define S_DIM 512

typedef __attribute__((ext_vector_type(8))) short short8;
typedef __attribute__((ext_vector_type(4))) float f32x4;

// ---------- helpers ----------
__device__ inline unsigned short f2bf(float x) {
    unsigned u = __builtin_bit_cast(unsigned, x);
    unsigned r = (u + 0x7fffu + ((u >> 16) & 1u)) >> 16;
    return (unsigned short)r;
}
__device__ inline float bf2f(unsigned short b) {
    unsigned u = ((unsigned)b) << 16;
    return __builtin_bit_cast(float, u);
}
__device__ inline float fast_tanh(float x) {
    float ax = __builtin_fabsf(x);
    float e  = __expf(-2.0f * ax);
    float r  = (1.0f - e) * __builtin_amdgcn_rcpf(1.0f + e);
    return __builtin_copysignf(r, x);
}

// Truncation split: x = bf2f(hi) + lo-term; residual exact, lo truncated ->
// total err <= 2^-16 |x|.  Pair-packed: low 16 bits of .x = element 0.
__device__ inline void split4(float4 v, uint2& hi, uint2& lo) {
    unsigned u0 = __builtin_bit_cast(unsigned, v.x);
    unsigned u1 = __builtin_bit_cast(unsigned, v.y);
    unsigned u2 = __builtin_bit_cast(unsigned, v.z);
    unsigned u3 = __builtin_bit_cast(unsigned, v.w);
    hi.x = (u0 >> 16) | (u1 & 0xFFFF0000u);
    hi.y = (u2 >> 16) | (u3 & 0xFFFF0000u);
    float r0 = v.x - __builtin_bit_cast(float, u0 & 0xFFFF0000u);
    float r1 = v.y - __builtin_bit_cast(float, u1 & 0xFFFF0000u);
    float r2 = v.z - __builtin_bit_cast(float, u2 & 0xFFFF0000u);
    float r3 = v.w - __builtin_bit_cast(float, u3 & 0xFFFF0000u);
    lo.x = (__builtin_bit_cast(unsigned, r0) >> 16)
         | (__builtin_bit_cast(unsigned, r1) & 0xFFFF0000u);
    lo.y = (__builtin_bit_cast(unsigned, r2) >> 16)
         | (__builtin_bit_cast(unsigned, r3) & 0xFFFF0000u);
}

// ---------- split-bf16 MFMA GEMM v3: C[M,N] = A @ B^T (+biases) ----------
// R5 post-mortem: moving B staging to per-ks global loads + in-register
// convert REGRESSED (~+43 us) -- L2 latency on the MFMA critical path and
// repeated split VALU.  v3 = R4's verified producer-staged structure (A and
// B hi/lo planes in LDS, BK=64, XOR swizzle, A prefetched one iter ahead,
// B issued pre-barrier) with the ll product dropped (validated in R5:
// absmax bit-identical).  3 MFMA per (mt,nt) pair instead of 4.
__global__ __launch_bounds__(256, 2)
void gemm_bt_mfma(const float* __restrict__ A, const float* __restrict__ Bm,
                  float* __restrict__ C,
                  const float* __restrict__ bias1, const float* __restrict__ bias2,
                  const int* __restrict__ ids, const float* __restrict__ emb,
                  int M, int N, int K)
{
    // LDS planes (bf16, [128 rows][64 k], row stride 128 B, swizzled):
    // Ahi @0, Alo @16K, Bhi @32K, Blo @48K  -> 64 KB total.
    __shared__ char smem[65536];

    const int tid  = threadIdx.x;
    const int lane = tid & 63;
    const int quad = lane >> 4;
    const int lcol = lane & 15;
    const int wv   = tid >> 6;
    const int wm   = (wv & 1) * 64;    // wave m-offset in tile
    const int wn   = (wv >> 1) * 64;   // wave n-offset in tile
    const int m0   = blockIdx.x * 128;
    const int n0   = blockIdx.y * 128;

    // staging map: thread covers rows rm+16i (i=0..7), float4-col kq.
    const int rm = tid >> 4;           // 0..15
    const int kq = tid & 15;           // 0..15  (float4 within BK=64)

    const float* arowp[8];
    const float* browp[8];
#pragma unroll
    for (int i = 0; i < 8; ++i) {
        int gm = m0 + rm + i * 16;
        arowp[i] = ids ? (emb + (size_t)ids[gm] * K) : (A + (size_t)gm * K);
        browp[i] = Bm + (size_t)(n0 + rm + i * 16) * K;
    }
    // per-thread swizzled LDS write offset (same for all planes)
    int woff[8];
#pragma unroll
    for (int i = 0; i < 8; ++i) {
        int m = rm + i * 16;
        woff[i] = (m * 128 + kq * 8) ^ ((m & 7) << 4);
    }

    f32x4 acc[4][4];
#pragma unroll
    for (int mt = 0; mt < 4; ++mt)
#pragma unroll
        for (int nt = 0; nt < 4; ++nt) acc[mt][nt] = (f32x4){0.f, 0.f, 0.f, 0.f};

    // prologue: prefetch A for iter 0
    float4 pa[8];
#pragma unroll
    for (int i = 0; i < 8; ++i)
        pa[i] = *(const float4*)(arowp[i] + kq * 4);

    for (int it = 0; it < 4; ++it) {
        const int kc = it * 64;
        // issue B loads early (before barrier; LDS untouched by them)
        float4 pb[8];
#pragma unroll
        for (int i = 0; i < 8; ++i)
            pb[i] = *(const float4*)(browp[i] + kc + kq * 4);

        if (it) __syncthreads();       // prior tile's reads complete

#pragma unroll
        for (int i = 0; i < 8; ++i) {
            uint2 hi, lo;
            split4(pa[i], hi, lo);
            *(uint2*)(smem + 0     + woff[i]) = hi;
            *(uint2*)(smem + 16384 + woff[i]) = lo;
        }
#pragma unroll
        for (int i = 0; i < 8; ++i) {
            uint2 hi, lo;
            split4(pb[i], hi, lo);
            *(uint2*)(smem + 32768 + woff[i]) = hi;
            *(uint2*)(smem + 49152 + woff[i]) = lo;
        }
        __syncthreads();

        if (it < 3) {                  // prefetch next A tile under compute
#pragma unroll
            for (int i = 0; i < 8; ++i)
                pa[i] = *(const float4*)(arowp[i] + kc + 64 + kq * 4);
        }

#pragma unroll
        for (int ks = 0; ks < 2; ++ks) {
            short8 aHi[4], aLo[4], bHi[4], bLo[4];
#pragma unroll
            for (int mt = 0; mt < 4; ++mt) {
                int m = wm + mt * 16 + lcol;
                int off = (m * 128 + ks * 64 + quad * 16) ^ ((m & 7) << 4);
                aHi[mt] = *(const short8*)(smem + off);
                aLo[mt] = *(const short8*)(smem + 16384 + off);
            }
#pragma unroll
            for (int nt = 0; nt < 4; ++nt) {
                int n = wn + nt * 16 + lcol;
                int off = (n * 128 + ks * 64 + quad * 16) ^ ((n & 7) << 4);
                bHi[nt] = *(const short8*)(smem + 32768 + off);
                bLo[nt] = *(const short8*)(smem + 49152 + off);
            }
#pragma unroll
            for (int mt = 0; mt < 4; ++mt)
#pragma unroll
                for (int nt = 0; nt < 4; ++nt) {
                    acc[mt][nt] = __builtin_amdgcn_mfma_f32_16x16x32_bf16(aHi[mt], bHi[nt], acc[mt][nt], 0, 0, 0);
                    acc[mt][nt] = __builtin_amdgcn_mfma_f32_16x16x32_bf16(aLo[mt], bHi[nt], acc[mt][nt], 0, 0, 0);
                    acc[mt][nt] = __builtin_amdgcn_mfma_f32_16x16x32_bf16(aHi[mt], bLo[nt], acc[mt][nt], 0, 0, 0);
                }
        }
    }

    // epilogue: D row = quad*4 + reg, col = lcol (per 16x16 fragment)
    float bv[4];
#pragma unroll
    for (int nt = 0; nt < 4; ++nt) {
        int gn = n0 + wn + nt * 16 + lcol;
        float v = 0.f;
        if (bias1) v += bias1[gn];
        if (bias2) v += bias2[gn];
        bv[nt] = v;
    }
#pragma unroll
    for (int mt = 0; mt < 4; ++mt) {
        int gmb = m0 + wm + mt * 16 + quad * 4;
#pragma unroll
        for (int r = 0; r < 4; ++r) {
            float* crow = C + (size_t)(gmb + r) * N + n0 + wn;
#pragma unroll
            for (int nt = 0; nt < 4; ++nt)
                crow[nt * 16 + lcol] = acc[mt][nt][r] + bv[nt];
        }
    }
}

// LDS-only barrier (R1: neutral vs __syncthreads; kept, documents intent).
__device__ inline void lds_barrier() {
    asm volatile("s_waitcnt lgkmcnt(0)" ::: "memory");
    __builtin_amdgcn_s_barrier();
    __builtin_amdgcn_sched_barrier(0);
}

// ---------- MFMA Elman scan (R3 version, unchanged): A-row-packed ----------
// hh and lh share B=wh: h_hi in A-row 0, h_lo in A-row 1 -> one MFMA gives
// hh (C reg[0]) and lh (C reg[1]).  hl via B=wl on same packed A.  32
// MFMA/wave/step; measured 437 us (step 2049 cyc vs 1242-cyc MFMA floor).
__global__ __launch_bounds__(512) __attribute__((amdgpu_waves_per_eu(2, 2)))
void rnn_scan_mfma(const float* __restrict__ pre, const float* __restrict__ Whh,
                   float* __restrict__ hout)
{
    const int tid  = threadIdx.x;
    const int wave = tid >> 6;
    const int lane = tid & 63;
    const int quad = lane >> 4;
    const int lcol = lane & 15;
    const int b    = blockIdx.x;

    // LDS layout (shorts): Hh[0]@0, Hl[0]@256, Hh[1]@512, Hl[1]@768.
    __shared__ short lds[1024];
    for (int i = tid; i < 1024; i += 512) lds[i] = 0;

    // --- W fragments: B-operand layout, lane holds W[n=.., k=quad*8+j] ---
    short8 wh[2][8], wl[2][8];
#pragma unroll
    for (int tile = 0; tile < 2; ++tile) {
        const int n = wave * 32 + tile * 16 + lcol;
        const float* wr = Whh + (size_t)n * D_DIM + quad * 8;
#pragma unroll
        for (int kt = 0; kt < 8; ++kt) {
            float4 x0 = *(const float4*)(wr + kt * 32);
            float4 x1 = *(const float4*)(wr + kt * 32 + 4);
            float xs[8] = {x0.x, x0.y, x0.z, x0.w, x1.x, x1.y, x1.z, x1.w};
            short8 hi8, lo8;
#pragma unroll
            for (int j = 0; j < 8; ++j) {
                unsigned short h = f2bf(xs[j]);
                unsigned short l = f2bf(xs[j] - bf2f(h));
                hi8[j] = (short)h;
                lo8[j] = (short)l;
            }
            wh[tile][kt] = hi8;
            wl[tile][kt] = lo8;
        }
    }

    const bool active = (lane < 16);           // quad==0 holds C rows 0..3
    const int n0 = wave * 32 + lcol;           // tile 0 unit
    const int n1 = n0 + 16;                    // tile 1 unit
    const size_t rowbase = (size_t)b * T_DIM * D_DIM;

    // Persistent packed A fragment: row 0 (lanes lcol==0) = h_hi chunk,
    // row 1 (lanes lcol==1) = h_lo chunk, rows 2..15 permanently zero.
    const short8 ZS = {0, 0, 0, 0, 0, 0, 0, 0};
    short8 aP[8];
#pragma unroll
    for (int kt = 0; kt < 8; ++kt) aP[kt] = ZS;

    const int aq = quad * 8;                   // k-chunk within buffer

    // 2-step-deep pre pipeline: pv = step t, nv = step t+1
    float pv0 = 0.f, pv1 = 0.f, nv0 = 0.f, nv1 = 0.f;
    if (active) {
        pv0 = pre[rowbase + n0];
        pv1 = pre[rowbase + n1];
        nv0 = pre[rowbase + D_DIM + n0];
        nv1 = pre[rowbase + D_DIM + n1];
    }
    lds_barrier();

    const f32x4 Z = {0.f, 0.f, 0.f, 0.f};

    for (int t = 0; t < T_DIM; ++t) {
        // prefetch step t+2's pre
        float qv0 = 0.f, qv1 = 0.f;
        if (active && t + 2 < T_DIM) {
            const float* p2 = pre + rowbase + (size_t)(t + 2) * D_DIM;
            qv0 = p2[n0];
            qv1 = p2[n1];
        }

        // exec-masked A loads: lanes lcol==0 read h_hi, lcol==1 read h_lo
        const int bh = (t & 1) ? 512 : 0;
        if (lcol < 2) {
            const short* pa = lds + bh + lcol * 256 + aq;
#pragma unroll
            for (int kt = 0; kt < 8; ++kt)
                aP[kt] = *(const short8*)(pa + kt * 32);
        }

        // 4 chains: a1* (B=wh: row0=hh, row1=lh), a2* (B=wl: row0=hl)
        f32x4 a1t0, a1t1, a2t0, a2t1;
        a1t0 = __builtin_amdgcn_mfma_f32_16x16x32_bf16(aP[0], wh[0][0], Z, 0, 0, 0);
        a1t1 = __builtin_amdgcn_mfma_f32_16x16x32_bf16(aP[0], wh[1][0], Z, 0, 0, 0);
        a2t0 = __builtin_amdgcn_mfma_f32_16x16x32_bf16(aP[0], wl[0][0], Z, 0, 0, 0);
        a2t1 = __builtin_amdgcn_mfma_f32_16x16x32_bf16(aP[0], wl[1][0], Z, 0, 0, 0);
#pragma unroll
        for (int kt = 1; kt < 8; ++kt) {
            a1t0 = __builtin_amdgcn_mfma_f32_16x16x32_bf16(aP[kt], wh[0][kt], a1t0, 0, 0, 0);
            a1t1 = __builtin_amdgcn_mfma_f32_16x16x32_bf16(aP[kt], wh[1][kt], a1t1, 0, 0, 0);
            a2t0 = __builtin_amdgcn_mfma_f32_16x16x32_bf16(aP[kt], wl[0][kt], a2t0, 0, 0, 0);
            a2t1 = __builtin_amdgcn_mfma_f32_16x16x32_bf16(aP[kt], wl[1][kt], a2t1, 0, 0, 0);
        }

        // epilogue: lanes 0..15 hold C rows 0 (reg 0: hh/hl) and 1 (reg 1: lh)
        if (active) {
            const int wH = (t & 1) ? 0 : 512;   // write the other buffer
            float x0 = a1t0[0] + a1t0[1] + a2t0[0] + pv0;
            float x1 = a1t1[0] + a1t1[1] + a2t1[0] + pv1;
            float h0 = fast_tanh(x0);
            float h1 = fast_tanh(x1);
            hout[rowbase + (size_t)t * D_DIM + n0] = h0;   // stays in flight
            hout[rowbase + (size_t)t * D_DIM + n1] = h1;
            unsigned short h0h = f2bf(h0);
            unsigned short h0l = f2bf(h0 - bf2f(h0h));
            unsigned short h1h = f2bf(h1);
            unsigned short h1l = f2bf(h1 - bf2f(h1h));
            lds[wH + n0]       = (short)h0h;
            lds[wH + n1]       = (short)h1h;
            lds[wH + 256 + n0] = (short)h0l;
            lds[wH + 256 + n1] = (short)h1l;
        }
        pv0 = nv0; pv1 = nv1;
        nv0 = qv0; nv1 = qv1;
        lds_barrier();
    }
}

extern "C" void kernel_launch(void* const* d_in, const int* in_sizes, int n_in,
                              void* d_out, int out_size, void* d_ws, size_t ws_size,
                              hipStream_t stream)
{
    const int*   ids    = (const int*)  d_in[0];
    const float* emb    = (const float*)d_in[1];
    const float* W_ih0  = (const float*)d_in[2];
    const float* W_hh0  = (const float*)d_in[3];
    const float* b_ih0  = (const float*)d_in[4];
    const float* b_hh0  = (const float*)d_in[5];
    const float* W_ih1  = (const float*)d_in[6];
    const float* W_hh1  = (const float*)d_in[7];
    const float* b_ih1  = (const float*)d_in[8];
    const float* b_hh1  = (const float*)d_in[9];
    const float* W_head = (const float*)d_in[10];

    float* out = (float*)d_out;
    const int M = B_DIM * T_DIM;              // 65536
    float* pre0 = out;                        // d_out doubles as scratch
    float* pre1 = out + (size_t)M * D_DIM;
    float* h1   = (float*)d_ws;               // 64 MB of ws
    float* h2   = h1;

    // pre0 = emb[ids] @ W_ih0^T + (b_ih0 + b_hh0)
    gemm_bt_mfma<<<dim3(M / 128, D_DIM / 128), dim3(256), 0, stream>>>(
        nullptr, W_ih0, pre0, b_ih0, b_hh0, ids, emb, M, D_DIM, D_DIM);
    // layer-0 recurrence (MFMA, A-row-packed split-bf16, 1 batch row/block)
    rnn_scan_mfma<<<dim3(B_DIM), dim3(512), 0, stream>>>(pre0, W_hh0, h1);
    // pre1 = h1 @ W_ih1^T + (b_ih1 + b_hh1)
    gemm_bt_mfma<<<dim3(M / 128, D_DIM / 128), dim3(256), 0, stream>>>(
        h1, W_ih1, pre1, b_ih1, b_hh1, nullptr, nullptr, M, D_DIM, D_DIM);
    // layer-1 recurrence
    rnn_scan_mfma<<<dim3(B_DIM), dim3(512), 0, stream>>>(pre1, W_hh1, h2);
    // logits = h2 @ W_head^T
    gemm_bt_mfma<<<dim3(M / 128, S_DIM / 128), dim3(256), 0, stream>>>(
        h2, W_head, out, nullptr, nullptr, nullptr, nullptr, M, S_DIM, D_DIM);
}